// Round 7
// 471.539 us; speedup vs baseline: 1.1675x; 1.1675x over previous
//
#include <hip/hip_runtime.h>

// out[m,n] = sum_k f16(x[m,k]) * W[n,k],  W = codebook[indices].reshape(4096,4096)
// M=8192, N=4096, K=4096, codebook 256x8. x/out are bf16 on the wire (verified);
// cb/idx dtypes sniffed on-device.
//
// FAST PATH (ws_size >= 96MiB+4KiB): detect -> dequant W (f16, ws+0) ->
//   cvt x (f16, ws+32MiB) -> 256x256 8-phase GEMM (BK=64, 8 waves, 128KiB LDS,
//   counted vmcnt(4), setprio around MFMA, XOR swizzle folded into global src,
//   XCD-aware block swizzle).  [prev 128x128 m97-structure: 353us, MfmaUtil 35%]
// FALLBACK (small ws): round-3 fused kernel, zero workspace (proven, 920us).
//
// [rounds 1-6: infra failures (4x GPUAcquisitionTimeout never ran; 2x
//  container-failed, interleaved -> host instability on acmh18u).
//  Structural audit: no hang possible (waitcnts always retire, barrier
//  counts wave-uniform, static loop bounds), no OOB. Resubmitting
//  unchanged. Pre-commitment: a future container-failure (not timeout)
//  -> submit round-0 baseline as infra/kernel split test.]

typedef _Float16 f16;
typedef _Float16 f16x8 __attribute__((ext_vector_type(8)));
typedef float f32x4 __attribute__((ext_vector_type(4)));

#define KDIM 4096
#define NDIM 4096
#define MDIM 8192

struct Flags { int cb_mode; int x_bf16; int idx64; int pad; };

__device__ inline float bf16_to_f32(unsigned short w) {
    union { unsigned u; float f; } c; c.u = ((unsigned)w) << 16; return c.f;
}
__device__ inline unsigned short f32_to_bf16(float f) {
    union { float f; unsigned u; } c; c.f = f;
    unsigned r = c.u + 0x7FFFu + ((c.u >> 16) & 1u);   // RNE
    return (unsigned short)(r >> 16);
}

// ============================ FAST PATH ======================================

__global__ __launch_bounds__(256) void crom_detect(const unsigned short* __restrict__ cbw,
                                                   const unsigned short* __restrict__ xw,
                                                   const unsigned* __restrict__ idxw,
                                                   Flags* __restrict__ flags) {
    __shared__ int cnt[4];
    const int t = threadIdx.x;
    if (t < 4) cnt[t] = 0;
    __syncthreads();
    int c_cb = 0, c_f32ok = 1, c_x = 0, c_z = 0;
    for (int j = 0; j < 8; ++j) {
        int e5 = (cbw[t * 8 + j] >> 10) & 31;         // f16 exp: f16 ~32%, bf16-bits ~99%
        c_cb += (e5 == 15) || (e5 == 16);
    }
    const float* cbf = (const float*)cbw;             // f32 test: exact f16 round-trip
    for (int j = 0; j < 4; ++j) {
        float v = cbf[t * 4 + j];
        if (!(__builtin_fabsf(v) < 1024.0f)) c_f32ok = 0;
        else { f16 h = (f16)v; if ((float)h != v) c_f32ok = 0; }
    }
    for (int j = 0; j < 8; ++j) {
        int e8 = (xw[t * 8 + j] >> 7) & 255;          // bf16 exp: bf16 ~100%, f32-halves ~53%
        c_x += (e8 >= 115) && (e8 <= 131);
    }
    for (int j = 1; j < 8; j += 2) c_z += (idxw[t * 8 + j] == 0);  // i64 high words
    atomicAdd(&cnt[0], c_cb);
    atomicAdd(&cnt[1], c_f32ok);
    atomicAdd(&cnt[2], c_x);
    atomicAdd(&cnt[3], c_z);
    __syncthreads();
    if (t == 0) {
        flags->cb_mode = (cnt[1] == 256) ? 2 : ((cnt[0] > 1300) ? 1 : 0); // 0=f16,1=bf16,2=f32
        flags->x_bf16  = cnt[2] > 1600;
        flags->idx64   = cnt[3] > 512;
    }
}

// gather codes -> dense W[N][K] f16 (one 16B code per thread)
__global__ __launch_bounds__(256) void crom_dequant(const void* __restrict__ idxraw,
                                                    const void* __restrict__ cbraw,
                                                    uint4* __restrict__ W,
                                                    const Flags* __restrict__ flags) {
    __shared__ __align__(16) f16 cbL[256 * 8];
    const int t = threadIdx.x;
    const int cb_mode = flags->cb_mode;
    if (cb_mode == 2) {
        const float* cf = (const float*)cbraw;
        f16x8 h;
        for (int j = 0; j < 8; ++j) h[j] = (f16)cf[t * 8 + j];
        *(f16x8*)&cbL[t * 8] = h;
    } else if (cb_mode == 1) {
        const unsigned short* cw = (const unsigned short*)cbraw;
        f16x8 h;
        for (int j = 0; j < 8; ++j) h[j] = (f16)bf16_to_f32(cw[t * 8 + j]);
        *(f16x8*)&cbL[t * 8] = h;
    } else {
        ((uint4*)cbL)[t] = ((const uint4*)cbraw)[t];
    }
    __syncthreads();
    int i = blockIdx.x * 256 + t;                     // 2,097,152 codes
    int code = flags->idx64 ? (int)((const long long*)idxraw)[i]
                            : ((const int*)idxraw)[i];
    W[i] = *(const uint4*)&cbL[code * 8];
}

// x -> f16, 8 elements/thread
__global__ __launch_bounds__(256) void crom_cvt_x(const void* __restrict__ X,
                                                  f16x8* __restrict__ Xh,
                                                  const Flags* __restrict__ flags) {
    int i = blockIdx.x * 256 + threadIdx.x;           // 4,194,304 groups of 8
    f16x8 h;
    if (flags->x_bf16) {
        ushort4 a = ((const ushort4*)X)[2 * i];
        ushort4 b = ((const ushort4*)X)[2 * i + 1];
        h[0] = (f16)bf16_to_f32(a.x); h[1] = (f16)bf16_to_f32(a.y);
        h[2] = (f16)bf16_to_f32(a.z); h[3] = (f16)bf16_to_f32(a.w);
        h[4] = (f16)bf16_to_f32(b.x); h[5] = (f16)bf16_to_f32(b.y);
        h[6] = (f16)bf16_to_f32(b.z); h[7] = (f16)bf16_to_f32(b.w);
    } else {
        float4 a = ((const float4*)X)[2 * i];
        float4 b = ((const float4*)X)[2 * i + 1];
        h[0] = (f16)a.x; h[1] = (f16)a.y; h[2] = (f16)a.z; h[3] = (f16)a.w;
        h[4] = (f16)b.x; h[5] = (f16)b.y; h[6] = (f16)b.z; h[7] = (f16)b.w;
    }
    Xh[i] = h;
}

// --- 256x256 8-phase GEMM ----------------------------------------------------
// LDS slot (row, j) holds global k-chunk j ^ (row&7) (swizzle folded into the
// global source address of global_load_lds; proven conflict-free).
// A half-tiles: H0 = rows {0-63, 128-191}, H1 = rows {64-127, 192-255}
//   (qm=0 rows / qm=1 rows for both M-waves).
// B half-tiles: H0 = rows r with (r&32)==0, H1 = (r&32)==32 (qn=0 / qn=1 rows).
// Region liveness per K-tile (phases q00,q01,q10,q11): A.H0 read only at q00,
// A.H1 only at q10; B.H0 only at q00 (held in regs for q10), B.H1 only at q01.
// Issue schedule per iteration (t0 even in buf0 @p0-3, t1 in buf1 @p4-7):
//   p0: A[buf1].H1 (kt=t0+1)   p1: B[buf1].H1 (t0+1)
//   p2: A[buf0].H0 (t0+2)      p3: B[buf0].H0 (t0+2)   tail vmcnt(4)
//   p4: A[buf0].H1 (t0+2)      p5: B[buf0].H1 (t0+2)
//   p6: A[buf1].H0 (t0+3)      p7: B[buf1].H0 (t0+3)   tail vmcnt(4)
// Every overwrite is issued after the phase where its region's last read
// completed (lgkmcnt(0) precedes the phase-end barrier). vmcnt(4) at each
// K-tile boundary leaves exactly the 2 newest half-tiles (4 loads) in flight.

__device__ __forceinline__ void stage_A(const f16* __restrict__ A, f16* dstbuf,
                                        int m0, int kt, int half, int w, int l) {
#pragma unroll
    for (int it = 0; it < 2; ++it) {
        const int gb = it * 512 + w * 64;             // wave-base granule
        const int g  = gb + l;
        const int lrl = g >> 3, j = g & 7;
        const int r  = ((lrl >> 6) << 7) + (half << 6) + (lrl & 63);
        const int sc = j ^ (r & 7);
        const f16* src = A + (size_t)(m0 + r) * KDIM + kt * 64 + sc * 8;
        const int lrb = gb >> 3;
        const int rb  = ((lrb >> 6) << 7) + (half << 6) + (lrb & 63);
        __builtin_amdgcn_global_load_lds(
            (const __attribute__((address_space(1))) void*)src,
            (__attribute__((address_space(3))) void*)(dstbuf + rb * 64), 16, 0, 0);
    }
}

__device__ __forceinline__ void stage_B(const f16* __restrict__ B, f16* dstbuf,
                                        int n0, int kt, int half, int w, int l) {
#pragma unroll
    for (int it = 0; it < 2; ++it) {
        const int gb = it * 512 + w * 64;
        const int g  = gb + l;
        const int lrl = g >> 3, j = g & 7;
        const int r  = ((lrl >> 5) << 6) + (half << 5) + (lrl & 31);
        const int sc = j ^ (r & 7);
        const f16* src = B + (size_t)(n0 + r) * KDIM + kt * 64 + sc * 8;
        const int lrb = gb >> 3;
        const int rb  = ((lrb >> 5) << 6) + (half << 5) + (lrb & 31);
        __builtin_amdgcn_global_load_lds(
            (const __attribute__((address_space(1))) void*)src,
            (__attribute__((address_space(3))) void*)(dstbuf + rb * 64), 16, 0, 0);
    }
}

#define VMW(n) do { asm volatile("s_waitcnt vmcnt(" #n ")" ::: "memory"); \
                    __builtin_amdgcn_sched_barrier(0); } while (0)

#define LOAD_AF(Asb, QM)                                                      \
    _Pragma("unroll")                                                         \
    for (int mt = 0; mt < 4; ++mt) {                                          \
        const int ro = (arow + (QM) * 64 + mt * 16) * 64;                     \
        af[mt][0] = *(const f16x8*)&(Asb)[ro + c0];                           \
        af[mt][1] = *(const f16x8*)&(Asb)[ro + c1];                           \
    }

#define LOAD_BF(Bsb, QN, bfx)                                                 \
    _Pragma("unroll")                                                         \
    for (int nt = 0; nt < 2; ++nt) {                                          \
        const int ro = (brow + (QN) * 32 + nt * 16) * 64;                     \
        bfx[nt][0] = *(const f16x8*)&(Bsb)[ro + c0];                          \
        bfx[nt][1] = *(const f16x8*)&(Bsb)[ro + c1];                          \
    }

#define MFMA16(QM, QN, bfx)                                                   \
    _Pragma("unroll")                                                         \
    for (int ks = 0; ks < 2; ++ks)                                            \
        _Pragma("unroll")                                                     \
        for (int mt = 0; mt < 4; ++mt)                                        \
            _Pragma("unroll")                                                 \
            for (int nt = 0; nt < 2; ++nt)                                    \
                acc[(QM) * 4 + mt][(QN) * 2 + nt] =                           \
                    __builtin_amdgcn_mfma_f32_16x16x32_f16(                   \
                        af[mt][ks], bfx[nt][ks],                              \
                        acc[(QM) * 4 + mt][(QN) * 2 + nt], 0, 0, 0);

#define BAR_MFMA(QM, QN, bfx, TAIL)                                           \
    __builtin_amdgcn_s_barrier();                                             \
    asm volatile("s_waitcnt lgkmcnt(0)" ::: "memory");                        \
    __builtin_amdgcn_sched_barrier(0);                                        \
    __builtin_amdgcn_s_setprio(1);                                            \
    MFMA16(QM, QN, bfx);                                                      \
    __builtin_amdgcn_s_setprio(0);                                            \
    TAIL;                                                                     \
    __builtin_amdgcn_s_barrier();

__global__ __launch_bounds__(512, 2) void crom_gemm(const f16* __restrict__ A,
                                                    const f16* __restrict__ B,
                                                    void* __restrict__ Cout,
                                                    const Flags* __restrict__ flags) {
    __shared__ __align__(16) f16 As[2][256 * 64];     // 64 KiB
    __shared__ __align__(16) f16 Bs[2][256 * 64];     // 64 KiB

    const int tid  = threadIdx.x;
    const int w    = tid >> 6;
    const int l    = tid & 63;
    const int quad = l >> 4;
    const int lr   = l & 15;
    const int wm   = w >> 2;                          // 0..1 (M)
    const int wn   = w & 3;                           // 0..3 (N)

    // XCD-aware bijective swizzle: nwg=512 = 8 XCDs x 64 contiguous tiles.
    const int bid = blockIdx.x;
    const int swz = (bid & 7) * 64 + (bid >> 3);
    const int m0  = (swz >> 4) * 256;                 // 32 M-tiles
    const int n0  = (swz & 15) * 256;                 // 16 N-tiles

    const int c0 = (quad ^ (lr & 7)) * 8;             // k-chunk slots (swizzled)
    const int c1 = ((4 + quad) ^ (lr & 7)) * 8;
    const int arow = wm * 128 + lr;                   // + QM*64 + mt*16
    const int brow = wn * 64 + lr;                    // + QN*32 + nt*16

    f32x4 acc[8][4] = {};
    f16x8 af[4][2], bf0[2][2], bf1[2][2];

    // prologue: K-tile 0 full + K-tile 1 {A.H0, B.H0}; wait K0 landed.
    stage_A(A, As[0], m0, 0, 0, w, l);
    stage_A(A, As[0], m0, 0, 1, w, l);
    stage_B(B, Bs[0], n0, 0, 0, w, l);
    stage_B(B, Bs[0], n0, 0, 1, w, l);
    stage_A(A, As[1], m0, 1, 0, w, l);
    stage_B(B, Bs[1], n0, 1, 0, w, l);
    VMW(4);
    __builtin_amdgcn_s_barrier();

    for (int i = 0; i < 31; ++i) {
        const int t0 = 2 * i;
        // ---- K-tile t0 (buf0) ----
        LOAD_AF(As[0], 0); LOAD_BF(Bs[0], 0, bf0);
        stage_A(A, As[1], m0, t0 + 1, 1, w, l);
        BAR_MFMA(0, 0, bf0, );
        LOAD_BF(Bs[0], 1, bf1);
        stage_B(B, Bs[1], n0, t0 + 1, 1, w, l);
        BAR_MFMA(0, 1, bf1, );
        LOAD_AF(As[0], 1);
        stage_A(A, As[0], m0, t0 + 2, 0, w, l);
        BAR_MFMA(1, 0, bf0, );
        stage_B(B, Bs[0], n0, t0 + 2, 0, w, l);
        BAR_MFMA(1, 1, bf1, VMW(4));
        // ---- K-tile t0+1 (buf1) ----
        LOAD_AF(As[1], 0); LOAD_BF(Bs[1], 0, bf0);
        stage_A(A, As[0], m0, t0 + 2, 1, w, l);
        BAR_MFMA(0, 0, bf0, );
        LOAD_BF(Bs[1], 1, bf1);
        stage_B(B, Bs[0], n0, t0 + 2, 1, w, l);
        BAR_MFMA(0, 1, bf1, );
        LOAD_AF(As[1], 1);
        stage_A(A, As[1], m0, t0 + 3, 0, w, l);
        BAR_MFMA(1, 0, bf0, );
        stage_B(B, Bs[1], n0, t0 + 3, 0, w, l);
        BAR_MFMA(1, 1, bf1, VMW(4));
    }

    // peeled tail: t0=62 (buf0), t1=63 (buf1). Finish staging 63.H1, drain once.
    LOAD_AF(As[0], 0); LOAD_BF(Bs[0], 0, bf0);
    stage_A(A, As[1], m0, 63, 1, w, l);
    BAR_MFMA(0, 0, bf0, );
    LOAD_BF(Bs[0], 1, bf1);
    stage_B(B, Bs[1], n0, 63, 1, w, l);
    BAR_MFMA(0, 1, bf1, );
    LOAD_AF(As[0], 1);
    BAR_MFMA(1, 0, bf0, );
    BAR_MFMA(1, 1, bf1, VMW(0));
    LOAD_AF(As[1], 0); LOAD_BF(Bs[1], 0, bf0);
    BAR_MFMA(0, 0, bf0, );
    LOAD_BF(Bs[1], 1, bf1);
    BAR_MFMA(0, 1, bf1, );
    LOAD_AF(As[1], 1);
    BAR_MFMA(1, 0, bf0, );
    BAR_MFMA(1, 1, bf1, );

    // epilogue: C/D col(N)=lane&15, row(M)=quad*4+reg
    const int out_bf16 = flags->x_bf16;
    if (out_bf16) {
        unsigned short* Cb = (unsigned short*)Cout;
#pragma unroll
        for (int mt = 0; mt < 8; ++mt)
#pragma unroll
            for (int nt = 0; nt < 4; ++nt) {
                const int colg = n0 + wn * 64 + nt * 16 + lr;
#pragma unroll
                for (int r = 0; r < 4; ++r) {
                    const int rowg = m0 + wm * 128 + mt * 16 + quad * 4 + r;
                    Cb[(size_t)rowg * NDIM + colg] = f32_to_bf16(acc[mt][nt][r]);
                }
            }
    } else {
        float* Cf = (float*)Cout;
#pragma unroll
        for (int mt = 0; mt < 8; ++mt)
#pragma unroll
            for (int nt = 0; nt < 4; ++nt) {
                const int colg = n0 + wn * 64 + nt * 16 + lr;
#pragma unroll
                for (int r = 0; r < 4; ++r) {
                    const int rowg = m0 + wm * 128 + mt * 16 + quad * 4 + r;
                    Cf[(size_t)rowg * NDIM + colg] = acc[mt][nt][r];
                }
            }
    }
}

// ============================ FALLBACK (round-3 fused, proven) ===============

__global__ __launch_bounds__(256) void crom_fused(const void* __restrict__ xraw,
                                                  const void* __restrict__ cbraw,
                                                  const void* __restrict__ idxraw,
                                                  void* __restrict__ outraw) {
    __shared__ __align__(16) f16 cbL[256 * 8];
    __shared__ __align__(16) f16 Asf[128 * 64];
    __shared__ __align__(16) f16 Bsf[128 * 64];
    __shared__ int flagsL[4];

    const int t = threadIdx.x;
    {
        int c_cb = 0, c_f32ok = 1, c_x = 0, c_z = 0;
        const unsigned short* cbw = (const unsigned short*)cbraw;
        for (int j = 0; j < 8; ++j) {
            int e5 = (cbw[t * 8 + j] >> 10) & 31;
            c_cb += (e5 == 15) || (e5 == 16);
        }
        const float* cbf = (const float*)cbraw;
        for (int j = 0; j < 4; ++j) {
            float v = cbf[t * 4 + j];
            if (!(__builtin_fabsf(v) < 1024.0f)) c_f32ok = 0;
            else { f16 h = (f16)v; if ((float)h != v) c_f32ok = 0; }
        }
        const unsigned short* xw = (const unsigned short*)xraw;
        for (int j = 0; j < 8; ++j) {
            int e8 = (xw[t * 8 + j] >> 7) & 255;
            c_x += (e8 >= 115) && (e8 <= 131);
        }
        const unsigned* iw = (const unsigned*)idxraw;
        for (int j = 1; j < 8; j += 2) c_z += (iw[t * 8 + j] == 0);
        if (t < 4) flagsL[t] = 0;
        __syncthreads();
        atomicAdd(&flagsL[0], c_cb);
        atomicAdd(&flagsL[1], c_f32ok);
        atomicAdd(&flagsL[2], c_x);
        atomicAdd(&flagsL[3], c_z);
        __syncthreads();
    }
    const int cb_mode = (flagsL[1] == 256) ? 2 : ((flagsL[0] > 1300) ? 1 : 0);
    const int x_bf16  = flagsL[2] > 1600;
    const int idx64   = flagsL[3] > 512;

    if (cb_mode == 2) {
        const float* cf = (const float*)cbraw;
        f16x8 h;
        for (int j = 0; j < 8; ++j) h[j] = (f16)cf[t * 8 + j];
        *(f16x8*)&cbL[t * 8] = h;
    } else if (cb_mode == 1) {
        const unsigned short* cw = (const unsigned short*)cbraw;
        f16x8 h;
        for (int j = 0; j < 8; ++j) h[j] = (f16)bf16_to_f32(cw[t * 8 + j]);
        *(f16x8*)&cbL[t * 8] = h;
    } else {
        ((uint4*)cbL)[t] = ((const uint4*)cbraw)[t];
    }
    __syncthreads();

    const int m0 = blockIdx.y * 128;
    const int n0 = blockIdx.x * 128;
    const int w = t >> 6, l = t & 63, quad = l >> 4, lr = l & 15;
    const int wm = (w >> 1) * 64, wn = (w & 1) * 64;

    f32x4 acc[4][4] = {};

    for (int kb = 0; kb < KDIM / 64; ++kb) {
        const int k0 = kb * 64;
#pragma unroll
        for (int cc = 0; cc < 4; ++cc) {
            int c = cc * 256 + t, row = c >> 3, j = c & 7;
            int gc = j ^ (row & 7);
            f16x8 h;
            if (!x_bf16) {
                const float4* p = (const float4*)((const float*)xraw +
                                  (size_t)(m0 + row) * KDIM + k0 + gc * 8);
                float4 a = p[0], b = p[1];
                h[0] = (f16)a.x; h[1] = (f16)a.y; h[2] = (f16)a.z; h[3] = (f16)a.w;
                h[4] = (f16)b.x; h[5] = (f16)b.y; h[6] = (f16)b.z; h[7] = (f16)b.w;
            } else {
                const unsigned short* p = (const unsigned short*)xraw +
                                          (size_t)(m0 + row) * KDIM + k0 + gc * 8;
                ushort4 a = *(const ushort4*)p, b = *(const ushort4*)(p + 4);
                h[0] = (f16)bf16_to_f32(a.x); h[1] = (f16)bf16_to_f32(a.y);
                h[2] = (f16)bf16_to_f32(a.z); h[3] = (f16)bf16_to_f32(a.w);
                h[4] = (f16)bf16_to_f32(b.x); h[5] = (f16)bf16_to_f32(b.y);
                h[6] = (f16)bf16_to_f32(b.z); h[7] = (f16)bf16_to_f32(b.w);
            }
            *(f16x8*)&Asf[row * 64 + j * 8] = h;
        }
#pragma unroll
        for (int cc = 0; cc < 4; ++cc) {
            int c = cc * 256 + t, row = c >> 3, j = c & 7;
            int gc = j ^ (row & 7);
            int cpos = (n0 + row) * (KDIM / 8) + kb * 8 + gc;
            int code = idx64 ? (int)((const long long*)idxraw)[cpos]
                             : ((const int*)idxraw)[cpos];
            *(f16x8*)&Bsf[row * 64 + j * 8] = *(const f16x8*)&cbL[code * 8];
        }
        __syncthreads();

#pragma unroll
        for (int ks = 0; ks < 2; ++ks) {
            f16x8 afv[4], bfv[4];
            int gc = ks * 4 + quad;
            int cc2 = gc ^ (lr & 7);
#pragma unroll
            for (int mt = 0; mt < 4; ++mt)
                afv[mt] = *(const f16x8*)&Asf[(wm + mt * 16 + lr) * 64 + cc2 * 8];
#pragma unroll
            for (int nt = 0; nt < 4; ++nt)
                bfv[nt] = *(const f16x8*)&Bsf[(wn + nt * 16 + lr) * 64 + cc2 * 8];
#pragma unroll
            for (int mt = 0; mt < 4; ++mt)
#pragma unroll
                for (int nt = 0; nt < 4; ++nt)
                    acc[mt][nt] = __builtin_amdgcn_mfma_f32_16x16x32_f16(
                        afv[mt], bfv[nt], acc[mt][nt], 0, 0, 0);
        }
        __syncthreads();
    }

    if (x_bf16) {
        unsigned short* Cb = (unsigned short*)outraw;
#pragma unroll
        for (int mt = 0; mt < 4; ++mt)
#pragma unroll
            for (int nt = 0; nt < 4; ++nt) {
                int colg = n0 + wn + nt * 16 + lr;
#pragma unroll
                for (int r = 0; r < 4; ++r) {
                    int rowg = m0 + wm + mt * 16 + quad * 4 + r;
                    Cb[(size_t)rowg * NDIM + colg] = f32_to_bf16(acc[mt][nt][r]);
                }
            }
    } else {
        float* Cf = (float*)outraw;
#pragma unroll
        for (int mt = 0; mt < 4; ++mt)
#pragma unroll
            for (int nt = 0; nt < 4; ++nt) {
                int colg = n0 + wn + nt * 16 + lr;
#pragma unroll
                for (int r = 0; r < 4; ++r) {
                    int rowg = m0 + wm + mt * 16 + quad * 4 + r;
                    Cf[(size_t)rowg * NDIM + colg] = acc[mt][nt][r];
                }
            }
    }
}

// ============================ launcher =======================================

extern "C" void kernel_launch(void* const* d_in, const int* in_sizes, int n_in,
                              void* d_out, int out_size, void* d_ws, size_t ws_size,
                              hipStream_t stream) {
    (void)in_sizes; (void)n_in; (void)out_size;
    const void* x   = d_in[0];
    const void* cb  = d_in[1];
    const void* idx = d_in[2];

    const size_t NEED = (size_t)96 * 1024 * 1024 + 4096;

    if (ws_size >= NEED) {
        f16*   Wq    = (f16*)d_ws;                                        // 32 MiB
        f16*   Xh    = (f16*)((char*)d_ws + (size_t)32 * 1024 * 1024);    // 64 MiB
        Flags* flags = (Flags*)((char*)d_ws + (size_t)96 * 1024 * 1024);  // 16 B

        crom_detect<<<1, 256, 0, stream>>>((const unsigned short*)cb,
                                           (const unsigned short*)x,
                                           (const unsigned*)idx, flags);
        crom_dequant<<<2097152 / 256, 256, 0, stream>>>(idx, cb, (uint4*)Wq, flags);
        crom_cvt_x<<<(33554432 / 8) / 256, 256, 0, stream>>>(x, (f16x8*)Xh, flags);
        crom_gemm<<<dim3((MDIM / 256) * (NDIM / 256)), dim3(512), 0, stream>>>(
            Xh, Wq, d_out, flags);
    } else {
        dim3 grid(NDIM / 128, MDIM / 128);
        crom_fused<<<grid, 256, 0, stream>>>(x, cb, idx, d_out);
    }
}